// Round 3
// baseline (282.462 us; speedup 1.0000x reference)
//
#include <hip/hip_runtime.h>
#include <math.h>

// Tsit5 tableau
#define A21f 0.161f
#define A31f -0.008480655492356989f
#define A32f 0.335480655492357f
#define A41f 2.8971530571054935f
#define A42f -6.359448489975075f
#define A43f 4.3622954328695815f
#define A51f 5.325864828439257f
#define A52f -11.748883564062828f
#define A53f 7.4955393428898365f
#define A54f -0.09249506636175525f
#define A61f 5.86145544294642f
#define A62f -12.92096931784711f
#define A63f 8.159367898576159f
#define A64f -0.071584973281401f
#define A65f -0.028269050394068383f
#define B1f 0.09646076681806523f
#define B2f 0.01f
#define B3f 0.4798896504144996f
#define B4f 1.379008574103742f
#define B5f -3.290069515436081f
#define B6f 2.324710524099774f
#define E1f -0.00178001105222577714f
#define E2f -0.0008164344596567469f
#define E3f 0.007880878010261995f
#define E4f -0.1447110071732629f
#define E5f 0.5823571654525552f
#define E6f -0.45808210592918697f
#define E7f 0.015151515151515152f

#define WPB 4  // waves per block

// Fused rotate+FMA: acc += (row_ror:N of v) * w — ONE VALU inst (VOP2 DPP).
#define FMAC_RR(acc, v, w, N)                                              \
    asm("v_fmac_f32_dpp %0, %1, %2 row_ror:" #N " row_mask:0xf bank_mask:0xf" \
        : "+v"(acc) : "v"(v), "v"(w))

// acc += 16-element dot; W[k] pre-gathered so W[k]*(row_ror:k of v) matches.
#define DOT16(acc, W, v) do {            \
    acc = fmaf((W)[0], (v), acc);        \
    FMAC_RR(acc, v, (W)[1], 1);          \
    FMAC_RR(acc, v, (W)[2], 2);          \
    FMAC_RR(acc, v, (W)[3], 3);          \
    FMAC_RR(acc, v, (W)[4], 4);          \
    FMAC_RR(acc, v, (W)[5], 5);          \
    FMAC_RR(acc, v, (W)[6], 6);          \
    FMAC_RR(acc, v, (W)[7], 7);          \
    FMAC_RR(acc, v, (W)[8], 8);          \
    FMAC_RR(acc, v, (W)[9], 9);          \
    FMAC_RR(acc, v, (W)[10], 10);        \
    FMAC_RR(acc, v, (W)[11], 11);        \
    FMAC_RR(acc, v, (W)[12], 12);        \
    FMAC_RR(acc, v, (W)[13], 13);        \
    FMAC_RR(acc, v, (W)[14], 14);        \
    FMAC_RR(acc, v, (W)[15], 15);        \
} while (0)

// permlane16/32_swap are TWO-DESTINATION instructions. Rounds 1-2 failed
// because inline asm cannot express that safely (clang coalesced the two
// identically-valued operands into ONE register; one write clobbered the
// other). The builtin returns a 2-element vector, so the compiler itself
// allocates two distinct destination registers. Consumers below are
// direction-agnostic: per lane one result element is the unchanged self,
// the other is the xor-16/32 partner (which is which depends on row parity
// and the ISA's swap direction — we never need to know).
typedef unsigned uint2v __attribute__((ext_vector_type(2)));

__device__ __forceinline__ float xadd16(float x) {
#if __has_builtin(__builtin_amdgcn_permlane16_swap)
    uint2v r = __builtin_amdgcn_permlane16_swap(__float_as_uint(x), __float_as_uint(x),
                                                false, false);
    // self + partner in whichever order: IEEE-commutative -> bit-identical
    // to  x + __shfl_xor(x, 16).
    return __uint_as_float(r[0]) + __uint_as_float(r[1]);
#else
    return x + __shfl_xor(x, 16);
#endif
}

__device__ __forceinline__ float xadd32(float x) {
#if __has_builtin(__builtin_amdgcn_permlane32_swap)
    uint2v r = __builtin_amdgcn_permlane32_swap(__float_as_uint(x), __float_as_uint(x),
                                                false, false);
    return __uint_as_float(r[0]) + __uint_as_float(r[1]);
#else
    return x + __shfl_xor(x, 32);
#endif
}

// Pure xor-16 exchange: exactly one of {r0,r1} equals x per lane; the xor
// cancels it and leaves the partner's exact bits. Direction-proof.
__device__ __forceinline__ float xchg16(float x) {
#if __has_builtin(__builtin_amdgcn_permlane16_swap)
    uint2v r = __builtin_amdgcn_permlane16_swap(__float_as_uint(x), __float_as_uint(x),
                                                false, false);
    return __uint_as_float(r[0] ^ r[1] ^ __float_as_uint(x));
#else
    return __shfl_xor(x, 16);
#endif
}

// In-row reduce stage: x = ror_N(x) + x. Same single-register VOP2-DPP form
// as the proven FMAC_RR. ror:8 == xor:8 exactly; after stage 8 the value is
// 8-periodic in row position, and (p±4/2/1 mod 16) lands in the same residue
// class as p^4/2/1 whose value is bit-identical (commutativity induction) ->
// whole butterfly bit-identical to the xor-shuffle version.
#define ADD_ROR(x, N)                                                       \
    asm("v_add_f32_dpp %0, %0, %0 row_ror:" #N " row_mask:0xf bank_mask:0xf" \
        : "+v"(x))

// softplus(x) = max(x,0) + ln2 * log2(1 + 2^(-|x|*log2e))  (hw exp2/log2)
__device__ __forceinline__ float sp(float x) {
    float t = exp2f(-fabsf(x) * 1.44269504088896341f);
    return fmaxf(x, 0.0f) + 0.69314718055994531f * __log2f(1.0f + t);
}

__global__ __launch_bounds__(256)
__attribute__((amdgpu_waves_per_eu(4, 4)))
void ode_kernel(const float* __restrict__ x0s,
                const float* __restrict__ W1, const float* __restrict__ b1,
                const float* __restrict__ W2, const float* __restrict__ b2,
                const float* __restrict__ W3, const float* __restrict__ b3,
                const void* __restrict__ Tptr,
                float* __restrict__ out, int out_size, int B)
{
    const int wave = threadIdx.x >> 6;
    const int lane = threadIdx.x & 63;
    const int traj = blockIdx.x * WPB + wave;
    if (traj >= B) return;

    const int p = lane & 15;   // position within 16-lane DPP row
    const int g = lane >> 4;   // row-group 0..3
    const int godd = g & 1;
    const int jh = g >> 1;     // layer-2 input half

    // ---- one-time per-lane weight gathers in DPP-rotated order ----
    float W1a[16], W1b[16], W2r[16], W3a[16], W3b[16];
    const int r2 = p + 16 * godd;
#pragma unroll
    for (int k = 0; k < 16; ++k) {
        const int c = (p + k) & 15;
        W1a[k] = W1[p * 64 + 16 * g + c];
        W1b[k] = W1[(16 + p) * 64 + 16 * g + c];
        W2r[k] = W2[r2 * 32 + 16 * jh + c];
        W3a[k] = W3[lane * 32 + c];
        W3b[k] = W3[lane * 32 + 16 + c];
    }
#pragma unroll
    for (int k = 0; k < 16; ++k) {
        asm("" : "+v"(W1a[k]));
        asm("" : "+v"(W1b[k]));
        asm("" : "+v"(W2r[k]));
        asm("" : "+v"(W3a[k]));
        asm("" : "+v"(W3b[k]));
    }
    const float b1a = b1[p], b1b = b1[p + 16];
    const float b2r = b2[r2], b3r = b3[lane];

    // f(u): u distributed lane-wise (lane i holds u[i]); result distributed.
    auto f = [&](float u) -> float {
        // layer 1: 64 -> 32
        float a1a = 0.f, a1b = 0.f;
        DOT16(a1a, W1a, u);
        DOT16(a1b, W1b, u);
        a1a = xadd16(a1a);      // == a1a += __shfl_xor(a1a,16), bit-identical
        a1a = xadd32(a1a);
        a1b = xadd16(a1b);
        a1b = xadd32(a1b);
        float h1A = sp(a1a + b1a);   // h1[p]    (replicated x4)
        float h1B = sp(a1b + b1b);   // h1[16+p]
        // layer 2: 32 -> 32  (this lane handles row r2, input half jh)
        float S = jh ? h1B : h1A;
        float a2 = 0.f;
        DOT16(a2, W2r, S);
        a2 = xadd32(a2);
        float h2v = sp(a2 + b2r);          // h2[r2] (replicated x2)
        float other = xchg16(h2v);         // h2[p + 16*!godd]
        float h2A = godd ? other : h2v;    // h2[p]
        float h2B = godd ? h2v : other;    // h2[16+p]
        // layer 3: 32 -> 64, both halves combined in-lane
        float a3 = 0.f;
        DOT16(a3, W3a, h2A);
        DOT16(a3, W3b, h2B);
        return a3 + b3r;
    };

    int ti = *(const int*)Tptr;
    float Tf = (ti > 0 && ti < 1000000) ? (float)ti : *(const float*)Tptr;
    const float ts_step = Tf / 10.0f;

    float y = x0s[traj * 64 + lane];
    out[traj * 704 + lane] = y;

    float t = 0.0f;
    float dt = 1e-3f;
    int n = 0;

    float k1 = f(y);  // FSAL seed

    for (int iv = 1; iv <= 10; ++iv) {
        const float t_target = (iv == 10) ? Tf : ts_step * (float)iv;
        for (int it = 0; it < 64; ++it) {
            const float remaining = t_target - t;
            if (remaining <= 1e-12f) break;
            const float h = fminf(dt, fmaxf(remaining, 0.0f));

            float k2 = f(y + h * (A21f * k1));
            float k3 = f(y + h * (A31f * k1 + A32f * k2));
            float k4 = f(y + h * (A41f * k1 + A42f * k2 + A43f * k3));
            float k5 = f(y + h * (A51f * k1 + A52f * k2 + A53f * k3 + A54f * k4));
            float k6 = f(y + h * (A61f * k1 + A62f * k2 + A63f * k3 + A64f * k4 + A65f * k5));
            float y5 = y + h * (B1f * k1 + B2f * k2 + B3f * k3 + B4f * k4 + B5f * k5 + B6f * k6);
            float k7 = f(y5);
            float err = h * (E1f * k1 + E2f * k2 + E3f * k3 + E4f * k4 + E5f * k5 + E6f * k6 + E7f * k7);

            float scale = 1e-6f + 1e-3f * fmaxf(fabsf(y), fabsf(y5));
            float r = err / scale;
            float s = r * r;
            // 64-lane butterfly sum, bit-identical to xor-shuffle version:
            s = xadd32(s);          // stage 32
            s = xadd16(s);          // stage 16
            ADD_ROR(s, 8);          // stage 8 (ror8 == xor8)
            ADD_ROR(s, 4);          // stage 4
            ADD_ROR(s, 2);          // stage 2
            ADD_ROR(s, 1);          // stage 1
            float enorm = fmaxf(sqrtf(s * (1.0f / 64.0f)), 1e-10f);

            bool accept = enorm <= 1.0f;
            float fac = 0.9f * exp2f(-0.2f * __log2f(enorm));  // 0.9 * enorm^-0.2
            fac = fminf(fmaxf(fac, 0.1f), 5.0f);

            if (accept) { t += h; y = y5; k1 = k7; }
            dt = fmaxf(h * fac, 1e-8f);
            ++n;
        }
        out[traj * 704 + iv * 64 + lane] = y;
    }

    if (lane == 0) atomicAdd(out + (out_size - 1), (float)n);
}

__global__ void init_n(float* p) { *p = 0.0f; }

extern "C" void kernel_launch(void* const* d_in, const int* in_sizes, int n_in,
                              void* d_out, int out_size, void* d_ws, size_t ws_size,
                              hipStream_t stream) {
    const float* x0s = (const float*)d_in[0];
    const float* W1  = (const float*)d_in[1];
    const float* b1  = (const float*)d_in[2];
    const float* W2  = (const float*)d_in[3];
    const float* b2  = (const float*)d_in[4];
    const float* W3  = (const float*)d_in[5];
    const float* b3  = (const float*)d_in[6];
    const void*  Tp  = d_in[7];
    float* out = (float*)d_out;

    const int B = in_sizes[0] / 64;
    const int grid = (B + WPB - 1) / WPB;

    init_n<<<1, 1, 0, stream>>>(out + (out_size - 1));
    ode_kernel<<<grid, 256, 0, stream>>>(x0s, W1, b1, W2, b2, W3, b3, Tp,
                                         out, out_size, B);
}

// Round 5
// 190.989 us; speedup vs baseline: 1.4789x; 1.4789x over previous
//
#include <hip/hip_runtime.h>
#include <math.h>

// Tsit5 tableau
#define A21f 0.161f
#define A31f -0.008480655492356989f
#define A32f 0.335480655492357f
#define A41f 2.8971530571054935f
#define A42f -6.359448489975075f
#define A43f 4.3622954328695815f
#define A51f 5.325864828439257f
#define A52f -11.748883564062828f
#define A53f 7.4955393428898365f
#define A54f -0.09249506636175525f
#define A61f 5.86145544294642f
#define A62f -12.92096931784711f
#define A63f 8.159367898576159f
#define A64f -0.071584973281401f
#define A65f -0.028269050394068383f
#define B1f 0.09646076681806523f
#define B2f 0.01f
#define B3f 0.4798896504144996f
#define B4f 1.379008574103742f
#define B5f -3.290069515436081f
#define B6f 2.324710524099774f
#define E1f -0.00178001105222577714f
#define E2f -0.0008164344596567469f
#define E3f 0.007880878010261995f
#define E4f -0.1447110071732629f
#define E5f 0.5823571654525552f
#define E6f -0.45808210592918697f
#define E7f 0.015151515151515152f

#define WPB 4  // waves per block

// Fused rotate+FMA: acc += (row_ror:N of v) * w — ONE VALU inst (VOP2 DPP).
#define FMAC_RR(acc, v, w, N)                                              \
    asm("v_fmac_f32_dpp %0, %1, %2 row_ror:" #N " row_mask:0xf bank_mask:0xf" \
        : "+v"(acc) : "v"(v), "v"(w))

// acc += 16-element dot; W[k] pre-gathered so W[k]*(row_ror:k of v) matches.
#define DOT16(acc, W, v) do {            \
    acc = fmaf((W)[0], (v), acc);        \
    FMAC_RR(acc, v, (W)[1], 1);          \
    FMAC_RR(acc, v, (W)[2], 2);          \
    FMAC_RR(acc, v, (W)[3], 3);          \
    FMAC_RR(acc, v, (W)[4], 4);          \
    FMAC_RR(acc, v, (W)[5], 5);          \
    FMAC_RR(acc, v, (W)[6], 6);          \
    FMAC_RR(acc, v, (W)[7], 7);          \
    FMAC_RR(acc, v, (W)[8], 8);          \
    FMAC_RR(acc, v, (W)[9], 9);          \
    FMAC_RR(acc, v, (W)[10], 10);        \
    FMAC_RR(acc, v, (W)[11], 11);        \
    FMAC_RR(acc, v, (W)[12], 12);        \
    FMAC_RR(acc, v, (W)[13], 13);        \
    FMAC_RR(acc, v, (W)[14], 14);        \
    FMAC_RR(acc, v, (W)[15], 15);        \
} while (0)

// softplus(x) = max(x,0) + ln2 * log2(1 + 2^(-|x|*log2e))  (hw exp2/log2)
__device__ __forceinline__ float sp(float x) {
    float t = exp2f(-fabsf(x) * 1.44269504088896341f);
    return fmaxf(x, 0.0f) + 0.69314718055994531f * __log2f(1.0f + t);
}

__global__ __launch_bounds__(256)
__attribute__((amdgpu_waves_per_eu(4, 4)))
void ode_kernel(const float* __restrict__ x0s,
                const float* __restrict__ W1, const float* __restrict__ b1,
                const float* __restrict__ W2, const float* __restrict__ b2,
                const float* __restrict__ W3, const float* __restrict__ b3,
                const void* __restrict__ Tptr,
                float* __restrict__ out, int out_size, int B)
{
    const int wave = threadIdx.x >> 6;
    const int lane = threadIdx.x & 63;
    const int traj = blockIdx.x * WPB + wave;
    if (traj >= B) return;

    const int p = lane & 15;   // position within 16-lane DPP row
    const int g = lane >> 4;   // row-group 0..3
    const int godd = g & 1;
    const int jh = g >> 1;     // layer-2 input half

    // ---- one-time per-lane weight gathers in DPP-rotated order ----
    float W1a[16], W1b[16], W2r[16], W3a[16], W3b[16];
    const int r2 = p + 16 * godd;
#pragma unroll
    for (int k = 0; k < 16; ++k) {
        const int c = (p + k) & 15;
        W1a[k] = W1[p * 64 + 16 * g + c];
        W1b[k] = W1[(16 + p) * 64 + 16 * g + c];
        W2r[k] = W2[r2 * 32 + 16 * jh + c];
        W3a[k] = W3[lane * 32 + c];
        W3b[k] = W3[lane * 32 + 16 + c];
    }
    // VOLATILE pins: round-0's non-volatile asm("") pins were legally
    // REMATERIALIZED by clang (re-execute load+asm near each use) — that's
    // why VGPR_Count was 60 with 80 "pinned" floats, and why the inner loop
    // was full of weight re-loads (vmcnt stalls = the 28% VALU idle).
    // volatile forbids re-execution -> the 80 values must stay truly live
    // in registers for the whole kernel (~110 live fits the 128-VGPR budget
    // of waves_per_eu(4,4)).
#pragma unroll
    for (int k = 0; k < 16; ++k) {
        asm volatile("" : "+v"(W1a[k]));
        asm volatile("" : "+v"(W1b[k]));
        asm volatile("" : "+v"(W2r[k]));
        asm volatile("" : "+v"(W3a[k]));
        asm volatile("" : "+v"(W3b[k]));
    }
    const float b1a = b1[p], b1b = b1[p + 16];
    const float b2r = b2[r2], b3r = b3[lane];

    // f(u): u distributed lane-wise (lane i holds u[i]); result distributed.
    auto f = [&](float u) -> float {
        // layer 1: 64 -> 32
        float a1a = 0.f, a1b = 0.f;
        DOT16(a1a, W1a, u);
        DOT16(a1b, W1b, u);
        a1a += __shfl_xor(a1a, 16);
        a1a += __shfl_xor(a1a, 32);
        a1b += __shfl_xor(a1b, 16);
        a1b += __shfl_xor(a1b, 32);
        float h1A = sp(a1a + b1a);   // h1[p]    (replicated x4)
        float h1B = sp(a1b + b1b);   // h1[16+p]
        // layer 2: 32 -> 32  (this lane handles row r2, input half jh)
        float S = jh ? h1B : h1A;
        float a2 = 0.f;
        DOT16(a2, W2r, S);
        a2 += __shfl_xor(a2, 32);
        float h2v = sp(a2 + b2r);          // h2[r2] (replicated x2)
        float other = __shfl_xor(h2v, 16); // h2[p + 16*!godd]
        float h2A = godd ? other : h2v;    // h2[p]
        float h2B = godd ? h2v : other;    // h2[16+p]
        // layer 3: 32 -> 64, both halves combined in-lane
        float a3 = 0.f;
        DOT16(a3, W3a, h2A);
        DOT16(a3, W3b, h2B);
        return a3 + b3r;
    };

    int ti = *(const int*)Tptr;
    float Tf = (ti > 0 && ti < 1000000) ? (float)ti : *(const float*)Tptr;
    const float ts_step = Tf / 10.0f;

    float y = x0s[traj * 64 + lane];
    out[traj * 704 + lane] = y;

    float t = 0.0f;
    float dt = 1e-3f;
    int n = 0;

    float k1 = f(y);  // FSAL seed

    for (int iv = 1; iv <= 10; ++iv) {
        const float t_target = (iv == 10) ? Tf : ts_step * (float)iv;
        for (int it = 0; it < 64; ++it) {
            const float remaining = t_target - t;
            if (remaining <= 1e-12f) break;
            const float h = fminf(dt, fmaxf(remaining, 0.0f));

            float k2 = f(y + h * (A21f * k1));
            float k3 = f(y + h * (A31f * k1 + A32f * k2));
            float k4 = f(y + h * (A41f * k1 + A42f * k2 + A43f * k3));
            float k5 = f(y + h * (A51f * k1 + A52f * k2 + A53f * k3 + A54f * k4));
            float k6 = f(y + h * (A61f * k1 + A62f * k2 + A63f * k3 + A64f * k4 + A65f * k5));
            float y5 = y + h * (B1f * k1 + B2f * k2 + B3f * k3 + B4f * k4 + B5f * k5 + B6f * k6);
            float k7 = f(y5);
            float err = h * (E1f * k1 + E2f * k2 + E3f * k3 + E4f * k4 + E5f * k5 + E6f * k6 + E7f * k7);

            float scale = 1e-6f + 1e-3f * fmaxf(fabsf(y), fabsf(y5));
            float r = err / scale;
            float s = r * r;
#pragma unroll
            for (int m = 32; m >= 1; m >>= 1) s += __shfl_xor(s, m);
            float enorm = fmaxf(sqrtf(s * (1.0f / 64.0f)), 1e-10f);

            bool accept = enorm <= 1.0f;
            float fac = 0.9f * exp2f(-0.2f * __log2f(enorm));  // 0.9 * enorm^-0.2
            fac = fminf(fmaxf(fac, 0.1f), 5.0f);

            if (accept) { t += h; y = y5; k1 = k7; }
            dt = fmaxf(h * fac, 1e-8f);
            ++n;
        }
        out[traj * 704 + iv * 64 + lane] = y;
    }

    if (lane == 0) atomicAdd(out + (out_size - 1), (float)n);
}

__global__ void init_n(float* p) { *p = 0.0f; }

extern "C" void kernel_launch(void* const* d_in, const int* in_sizes, int n_in,
                              void* d_out, int out_size, void* d_ws, size_t ws_size,
                              hipStream_t stream) {
    const float* x0s = (const float*)d_in[0];
    const float* W1  = (const float*)d_in[1];
    const float* b1  = (const float*)d_in[2];
    const float* W2  = (const float*)d_in[3];
    const float* b2  = (const float*)d_in[4];
    const float* W3  = (const float*)d_in[5];
    const float* b3  = (const float*)d_in[6];
    const void*  Tp  = d_in[7];
    float* out = (float*)d_out;

    const int B = in_sizes[0] / 64;
    const int grid = (B + WPB - 1) / WPB;

    init_n<<<1, 1, 0, stream>>>(out + (out_size - 1));
    ode_kernel<<<grid, 256, 0, stream>>>(x0s, W1, b1, W2, b2, W3, b3, Tp,
                                         out, out_size, B);
}